// Round 7
// baseline (242.035 us; speedup 1.0000x reference)
//
#include <hip/hip_runtime.h>

#define DEV __device__ __forceinline__
#define KSIG (-1.442695041f)
#define KTANH (-2.885390082f)

typedef float f2 __attribute__((ext_vector_type(2)));
typedef float f4 __attribute__((ext_vector_type(4)));

DEV float fexp2(float x) { return __builtin_amdgcn_exp2f(x); }
DEV float frcp(float x) { return __builtin_amdgcn_rcpf(x); }
DEV float bperm(int a, float x) {
  return __int_as_float(__builtin_amdgcn_ds_bpermute(a, __float_as_int(x)));
}
DEV f2 pkfma(f2 a, f2 b, f2 c) { return __builtin_elementwise_fma(a, b, c); }

// Lane u of a 5-lane group owns state index j=u and gate rows
// {u,5+u,10+u,15+u} (i,f,g,o). kexp folded into weights/bias: sigmoid rows
// scaled by KSIG, g-row by KTANH; act = rcp(1+exp2(acc)), tanh = 2*act-1.
// 48 floats/lane — the ONLY footprint the allocator has tolerated (r0-r6).
struct CellP {
  f2 wx[4][2];
  f2 wh[4][2];
  float wx4[4], wh4[4];
  f2 b2[4];  // {bias, 0}
};

DEV void load_cellP(CellP& W, int u, const float* __restrict__ Wih,
                    const float* __restrict__ Whh,
                    const float* __restrict__ bih,
                    const float* __restrict__ bhh) {
#pragma unroll
  for (int rt = 0; rt < 4; ++rt) {  // 0=i 1=f 2=g 3=o
    int row = 5 * rt + u;
    float kx = (rt == 2) ? KTANH : KSIG;
    W.wx[rt][0] = (f2){kx * Wih[row * 5 + 0], kx * Wih[row * 5 + 1]};
    W.wx[rt][1] = (f2){kx * Wih[row * 5 + 2], kx * Wih[row * 5 + 3]};
    W.wx4[rt] = kx * Wih[row * 5 + 4];
    W.wh[rt][0] = (f2){kx * Whh[row * 5 + 0], kx * Whh[row * 5 + 1]};
    W.wh[rt][1] = (f2){kx * Whh[row * 5 + 2], kx * Whh[row * 5 + 3]};
    W.wh4[rt] = kx * Whh[row * 5 + 4];
    W.b2[rt] = (f2){kx * (bih[row] + bhh[row]), 0.f};
  }
}

// One cell timestep; returns this lane's own h_j(t). hAll: h(t-1) in, h(t) out.
DEV float stepP(const CellP& W, const f2 xp[2], float x4, float hAll[5],
                float& c, const int bp[5]) {
  f2 hp0 = (f2){hAll[0], hAll[1]};
  f2 hp1 = (f2){hAll[2], hAll[3]};
  float acc[4];
#pragma unroll
  for (int rt = 0; rt < 4; ++rt) {
    f2 a2 = pkfma(W.wh[rt][0], hp0, W.b2[rt]);
    a2 = pkfma(W.wh[rt][1], hp1, a2);
    a2 = pkfma(W.wx[rt][0], xp[0], a2);
    a2 = pkfma(W.wx[rt][1], xp[1], a2);
    float a = a2.x + a2.y;
    a = fmaf(W.wh4[rt], hAll[4], a);
    acc[rt] = fmaf(W.wx4[rt], x4, a);
  }
  float gi = frcp(1.f + fexp2(acc[0]));
  float gf = frcp(1.f + fexp2(acc[1]));
  float gg = fmaf(2.f, frcp(1.f + fexp2(acc[2])), -1.f);
  float go = frcp(1.f + fexp2(acc[3]));
  c = fmaf(gf, c, gi * gg);
  float th = fmaf(2.f, frcp(1.f + fexp2(KTANH * c)), -1.f);
  float h = go * th;
#pragma unroll
  for (int u2 = 0; u2 < 5; ++u2) hAll[u2] = bperm(bp[u2], h);
  return h;
}

// 4-timestep chunk of a [*][5] float stream: 20 floats = 5 aligned dwordx4
// (element base is 2560B-aligned). Double-buffered for prefetch depth ~4-8.
struct XBuf {
  f4 a, b, c, d, e;
};
DEV void xload(XBuf& bf, const float* __restrict__ px, int ch) {
  const f4* q = (const f4*)px + ch * 5;
  bf.a = q[0];
  bf.b = q[1];
  bf.c = q[2];
  bf.d = q[3];
  bf.e = q[4];
}
// Step s of a chunk consumes floats [5s..5s+4]:
//  s=0: a.xyzw b.x  s=1: b.yzw c.xy  s=2: c.zw d.xyz  s=3: d.w e.xyzw

// ---------------------------------------------------------------------------
// Kernel A: lstm1 and lstm2a as fully independent waves. NO LDS, NO barriers.
// wid < N1 -> lstm1 (writes h1last[B][5] at the end);
// wid >= N1 -> lstm2a (streams h2a[e][t][5] to workspace every step).
// 2*ceil(B/12) waves total (~2731 for B=16384) = 2.67 waves/SIMD resident —
// the most TLP of any round; time law is per-wave-step-cost / waves-per-SIMD.
// ---------------------------------------------------------------------------
__global__ __launch_bounds__(192, 3) void rnn_a_kernel(
    const float* __restrict__ x1, const float* __restrict__ x2,
    const float* __restrict__ Wih1, const float* __restrict__ Whh1,
    const float* __restrict__ bih1, const float* __restrict__ bhh1,
    const float* __restrict__ Wih2a, const float* __restrict__ Whh2a,
    const float* __restrict__ bih2a, const float* __restrict__ bhh2a,
    float* __restrict__ h2a, float* __restrict__ h1l, int B, int N1) {
  const int tid = threadIdx.x;
  const int wid = blockIdx.x * 3 + (tid >> 6);
  if (wid >= 2 * N1) return;  // safe: no barriers in this kernel
  const int l = tid & 63;
  int g = l / 5;
  const int u = l - 5 * g;
  const bool act = (g < 12);
  if (!act) g = 11;
  const bool r2 = (wid >= N1);
  const int e = (r2 ? wid - N1 : wid) * 12 + g;
  const int ec = (e < B) ? e : B - 1;

  CellP W;
  if (r2)
    load_cellP(W, u, Wih2a, Whh2a, bih2a, bhh2a);
  else
    load_cellP(W, u, Wih1, Whh1, bih1, bhh1);

  int bp[5];
#pragma unroll
  for (int k = 0; k < 5; ++k) bp[k] = (5 * g + k) * 4;

  const float* px = (r2 ? x2 : x1) + (size_t)ec * 640;
  const bool wr = r2 && act && (e < B);
  float* ps = h2a + (size_t)ec * 640 + u;  // [e][t][5] stream, this lane's j=u

  float hAll[5];
  float c = 0.f, hOwn = 0.f;
#pragma unroll
  for (int k = 0; k < 5; ++k) hAll[k] = 0.f;

#define SA1(S, xa, xb, xc, xd, xe)                  \
  {                                                 \
    f2 xin[2] = {(f2){xa, xb}, (f2){xc, xd}};       \
    hOwn = stepP(W, xin, xe, hAll, c, bp);          \
    if (wr) pst[(S) * 5] = hOwn;                    \
  }
#define CHUNKA(X)                                  \
  SA1(0, X.a.x, X.a.y, X.a.z, X.a.w, X.b.x)        \
  SA1(1, X.b.y, X.b.z, X.b.w, X.c.x, X.c.y)        \
  SA1(2, X.c.z, X.c.w, X.d.x, X.d.y, X.d.z)        \
  SA1(3, X.d.w, X.e.x, X.e.y, X.e.z, X.e.w)

  XBuf A0, B0;
  xload(A0, px, 0);
  for (int ch = 0; ch < 32; ch += 2) {
    xload(B0, px, (ch + 1 < 32) ? ch + 1 : 31);
    {
      float* pst = ps + (size_t)ch * 20;
      CHUNKA(A0);
    }
    xload(A0, px, (ch + 2 < 32) ? ch + 2 : 31);
    {
      float* pst = ps + (size_t)(ch + 1) * 20;
      CHUNKA(B0);
    }
  }
#undef SA1
#undef CHUNKA

  if (!r2 && act && e < B) h1l[(size_t)e * 5 + u] = hOwn;  // h1(127)
}

// ---------------------------------------------------------------------------
// Kernel B: lstm2b over the h2a[e][t][5] stream + fused FC stack.
// Block = 192 threads = 3 waves x 12 elements = 36 elements.
// ---------------------------------------------------------------------------
__global__ __launch_bounds__(192, 2) void rnn_b_kernel(
    const float* __restrict__ x1, const float* __restrict__ x2,
    const float* __restrict__ Wih2b, const float* __restrict__ Whh2b,
    const float* __restrict__ bih2b, const float* __restrict__ bhh2b,
    const float* __restrict__ W1, const float* __restrict__ b1,
    const float* __restrict__ W2, const float* __restrict__ b2,
    const float* __restrict__ W3, const float* __restrict__ b3,
    const float* __restrict__ W4, const float* __restrict__ b4,
    const float* __restrict__ W5, const float* __restrict__ b5,
    const float* __restrict__ h2a, const float* __restrict__ h1l,
    float* __restrict__ out, int B) {
  __shared__ float sIn[36][20];
  __shared__ float sA[36][32];
  __shared__ float sB[36][32];

  const int tid = threadIdx.x;
  const int w = tid >> 6;
  const int l = tid & 63;
  int g = l / 5;
  const int u = l - 5 * g;
  const bool act = (g < 12);
  if (!act) g = 11;
  const int el = w * 12 + g;
  const int e = blockIdx.x * 36 + el;
  const int ec = (e < B) ? e : B - 1;

  CellP W;
  load_cellP(W, u, Wih2b, Whh2b, bih2b, bhh2b);

  int bp[5];
#pragma unroll
  for (int k = 0; k < 5; ++k) bp[k] = (5 * g + k) * 4;

  const float* ph = h2a + (size_t)ec * 640;  // this element's h2a(t) stream

  float hAll[5];
  float c = 0.f, hOwn = 0.f;
#pragma unroll
  for (int k = 0; k < 5; ++k) hAll[k] = 0.f;

#define SB1(xa, xb, xc, xd, xe)                 \
  {                                             \
    f2 xin[2] = {(f2){xa, xb}, (f2){xc, xd}};   \
    hOwn = stepP(W, xin, xe, hAll, c, bp);      \
  }
#define CHUNKB(X)                              \
  SB1(X.a.x, X.a.y, X.a.z, X.a.w, X.b.x)       \
  SB1(X.b.y, X.b.z, X.b.w, X.c.x, X.c.y)       \
  SB1(X.c.z, X.c.w, X.d.x, X.d.y, X.d.z)       \
  SB1(X.d.w, X.e.x, X.e.y, X.e.z, X.e.w)

  XBuf A0, B0;
  xload(A0, ph, 0);
  for (int ch = 0; ch < 32; ch += 2) {
    xload(B0, ph, (ch + 1 < 32) ? ch + 1 : 31);
    CHUNKB(A0);
    xload(A0, ph, (ch + 2 < 32) ? ch + 2 : 31);
    CHUNKB(B0);
  }
#undef SB1
#undef CHUNKB

  // Stage FC inputs [x1_last, x2_last, h1, h2b] for the block's 36 elements.
  if (act) {
    sIn[el][u] = x1[(size_t)ec * 640 + 635 + u];
    sIn[el][5 + u] = x2[(size_t)ec * 640 + 635 + u];
    sIn[el][10 + u] = h1l[(size_t)ec * 5 + u];
    sIn[el][15 + u] = hOwn;  // h2b(127)
  }
  __syncthreads();

  // FC stack: task-split over 192 lanes; weights from global (L1-cached).
  for (int task = tid; task < 36 * 32; task += 192) {
    int e2 = task >> 5, n = task & 31;
    float acc = b1[n];
#pragma unroll
    for (int k = 0; k < 20; ++k) acc = fmaf(W1[n * 20 + k], sIn[e2][k], acc);
    sA[e2][n] = fmaxf(acc, 0.f);
  }
  __syncthreads();
  for (int task = tid; task < 36 * 32; task += 192) {
    int e2 = task >> 5, n = task & 31;
    float acc = b2[n];
#pragma unroll
    for (int k = 0; k < 32; ++k) acc = fmaf(W2[n * 32 + k], sA[e2][k], acc);
    sB[e2][n] = fmaxf(acc, 0.f);
  }
  __syncthreads();
  for (int task = tid; task < 36 * 16; task += 192) {
    int e2 = task >> 4, n = task & 15;
    float acc = b3[n];
#pragma unroll
    for (int k = 0; k < 32; ++k) acc = fmaf(W3[n * 32 + k], sB[e2][k], acc);
    sA[e2][n] = fmaxf(acc, 0.f);  // reuse sA cols 0..15
  }
  __syncthreads();
  for (int task = tid; task < 36 * 16; task += 192) {
    int e2 = task >> 4, n = task & 15;
    float acc = b4[n];
#pragma unroll
    for (int k = 0; k < 16; ++k) acc = fmaf(W4[n * 16 + k], sA[e2][k], acc);
    sB[e2][n] = fmaxf(acc, 0.f);
  }
  __syncthreads();
  for (int task = tid; task < 36 * 5; task += 192) {
    int e2 = task / 5, n = task - 5 * (task / 5);
    float acc = b5[n];
#pragma unroll
    for (int k = 0; k < 16; ++k) acc = fmaf(W5[n * 16 + k], sB[e2][k], acc);
    int ego = blockIdx.x * 36 + e2;
    if (ego < B) out[(size_t)ego * 5 + n] = acc;
  }
}

// ---------------------------------------------------------------------------
// Fallback (round-3 monolith, measured 119.5us) if workspace is too small.
// ---------------------------------------------------------------------------
__global__ __launch_bounds__(192, 2) void rnn_stag_kernel(
    const float* __restrict__ x1, const float* __restrict__ x2,
    const float* __restrict__ Wih1, const float* __restrict__ Whh1,
    const float* __restrict__ bih1, const float* __restrict__ bhh1,
    const float* __restrict__ Wih2a, const float* __restrict__ Whh2a,
    const float* __restrict__ bih2a, const float* __restrict__ bhh2a,
    const float* __restrict__ Wih2b, const float* __restrict__ Whh2b,
    const float* __restrict__ bih2b, const float* __restrict__ bhh2b,
    const float* __restrict__ W1, const float* __restrict__ b1,
    const float* __restrict__ W2, const float* __restrict__ b2,
    const float* __restrict__ W3, const float* __restrict__ b3,
    const float* __restrict__ W4, const float* __restrict__ b4,
    const float* __restrict__ W5, const float* __restrict__ b5,
    float* __restrict__ out, int B) {
  __shared__ float sIn[24][20];
  __shared__ float sA[24][32];
  __shared__ float sB[24][32];

  const int tid = threadIdx.x;
  const int w = tid >> 6;
  const int l = tid & 63;
  int g = l / 5;
  const int u = l - 5 * g;
  const bool act = (g < 12);
  if (!act) g = 11;
  const int base = blockIdx.x * 24;

  int bp[5];
#pragma unroll
  for (int k = 0; k < 5; ++k) bp[k] = (5 * g + k) * 4;

  if (w == 0) {
    CellP W;
    load_cellP(W, u, Wih1, Whh1, bih1, bhh1);
    const int e0 = base + 2 * g, e1 = e0 + 1;
    const int e0c = (e0 < B) ? e0 : B - 1;
    const int e1c = (e1 < B) ? e1 : B - 1;
    const float* p0 = x1 + (size_t)e0c * 640;
    const float* p1 = x1 + (size_t)e1c * 640;
    float h0[5], h1[5];
    float c0 = 0.f, c1 = 0.f, ho0 = 0.f, ho1 = 0.f;
#pragma unroll
    for (int k = 0; k < 5; ++k) {
      h0[k] = 0.f;
      h1[k] = 0.f;
    }
    f2 xa[2] = {(f2){p0[0], p0[1]}, (f2){p0[2], p0[3]}};
    f2 xb[2] = {(f2){p1[0], p1[1]}, (f2){p1[2], p1[3]}};
    float xa4 = p0[4], xb4 = p1[4];
    for (int t = 0; t < 128; ++t) {
      f2 xia[2] = {xa[0], xa[1]}, xib[2] = {xb[0], xb[1]};
      float xia4 = xa4, xib4 = xb4;
      const int tn = (t < 127) ? t + 1 : 127;
      xa[0] = (f2){p0[tn * 5 + 0], p0[tn * 5 + 1]};
      xa[1] = (f2){p0[tn * 5 + 2], p0[tn * 5 + 3]};
      xa4 = p0[tn * 5 + 4];
      xb[0] = (f2){p1[tn * 5 + 0], p1[tn * 5 + 1]};
      xb[1] = (f2){p1[tn * 5 + 2], p1[tn * 5 + 3]};
      xb4 = p1[tn * 5 + 4];
      ho0 = stepP(W, xia, xia4, h0, c0, bp);
      ho1 = stepP(W, xib, xib4, h1, c1, bp);
    }
    if (act) {
      sIn[2 * g][u] = x1[(size_t)e0c * 640 + 635 + u];
      sIn[2 * g][10 + u] = ho0;
      sIn[2 * g + 1][u] = x1[(size_t)e1c * 640 + 635 + u];
      sIn[2 * g + 1][10 + u] = ho1;
    }
  } else {
    CellP Wa, Wb;
    load_cellP(Wa, u, Wih2a, Whh2a, bih2a, bhh2a);
    load_cellP(Wb, u, Wih2b, Whh2b, bih2b, bhh2b);
    const int el = ((w == 1) ? 0 : 12) + g;
    const int e = base + el;
    const int ec = (e < B) ? e : B - 1;
    const float* px = x2 + (size_t)ec * 640;
    float hA[5], hB[5];
    float cA = 0.f, cB = 0.f, hoB = 0.f;
#pragma unroll
    for (int k = 0; k < 5; ++k) {
      hA[k] = 0.f;
      hB[k] = 0.f;
    }
    f2 xc[2] = {(f2){px[0], px[1]}, (f2){px[2], px[3]}};
    float xc4 = px[4];
    (void)stepP(Wa, xc, xc4, hA, cA, bp);
    xc[0] = (f2){px[5], px[6]};
    xc[1] = (f2){px[7], px[8]};
    xc4 = px[9];
    for (int t = 1; t < 128; ++t) {
      f2 xin[2] = {xc[0], xc[1]};
      float xin4 = xc4;
      const int tn = (t < 127) ? t + 1 : 127;
      xc[0] = (f2){px[tn * 5 + 0], px[tn * 5 + 1]};
      xc[1] = (f2){px[tn * 5 + 2], px[tn * 5 + 3]};
      xc4 = px[tn * 5 + 4];
      f2 hin[2] = {(f2){hA[0], hA[1]}, (f2){hA[2], hA[3]}};
      float hin4 = hA[4];
      (void)stepP(Wa, xin, xin4, hA, cA, bp);
      hoB = stepP(Wb, hin, hin4, hB, cB, bp);
    }
    {
      f2 hin[2] = {(f2){hA[0], hA[1]}, (f2){hA[2], hA[3]}};
      hoB = stepP(Wb, hin, hA[4], hB, cB, bp);
    }
    if (act) {
      sIn[el][5 + u] = x2[(size_t)ec * 640 + 635 + u];
      sIn[el][15 + u] = hoB;
    }
  }
  __syncthreads();

  for (int task = tid; task < 24 * 32; task += 192) {
    int e = task >> 5, n = task & 31;
    float acc = b1[n];
#pragma unroll
    for (int k = 0; k < 20; ++k) acc = fmaf(W1[n * 20 + k], sIn[e][k], acc);
    sA[e][n] = fmaxf(acc, 0.f);
  }
  __syncthreads();
  for (int task = tid; task < 24 * 32; task += 192) {
    int e = task >> 5, n = task & 31;
    float acc = b2[n];
#pragma unroll
    for (int k = 0; k < 32; ++k) acc = fmaf(W2[n * 32 + k], sA[e][k], acc);
    sB[e][n] = fmaxf(acc, 0.f);
  }
  __syncthreads();
  for (int task = tid; task < 24 * 16; task += 192) {
    int e = task >> 4, n = task & 15;
    float acc = b3[n];
#pragma unroll
    for (int k = 0; k < 32; ++k) acc = fmaf(W3[n * 32 + k], sB[e][k], acc);
    sA[e][n] = fmaxf(acc, 0.f);
  }
  __syncthreads();
  for (int task = tid; task < 24 * 16; task += 192) {
    int e = task >> 4, n = task & 15;
    float acc = b4[n];
#pragma unroll
    for (int k = 0; k < 16; ++k) acc = fmaf(W4[n * 16 + k], sA[e][k], acc);
    sB[e][n] = fmaxf(acc, 0.f);
  }
  __syncthreads();
  if (tid < 120) {
    int e = tid / 5, n = tid - 5 * (tid / 5);
    float acc = b5[n];
#pragma unroll
    for (int k = 0; k < 16; ++k) acc = fmaf(W5[n * 16 + k], sB[e][k], acc);
    int ego = base + e;
    if (ego < B) out[(size_t)ego * 5 + n] = acc;
  }
}

extern "C" void kernel_launch(void* const* d_in, const int* in_sizes, int n_in,
                              void* d_out, int out_size, void* d_ws,
                              size_t ws_size, hipStream_t stream) {
  const float* x1 = (const float*)d_in[0];
  const float* x2 = (const float*)d_in[1];
  const float* Wih1 = (const float*)d_in[2];
  const float* Whh1 = (const float*)d_in[3];
  const float* bih1 = (const float*)d_in[4];
  const float* bhh1 = (const float*)d_in[5];
  const float* Wih2a = (const float*)d_in[6];
  const float* Whh2a = (const float*)d_in[7];
  const float* bih2a = (const float*)d_in[8];
  const float* bhh2a = (const float*)d_in[9];
  const float* Wih2b = (const float*)d_in[10];
  const float* Whh2b = (const float*)d_in[11];
  const float* bih2b = (const float*)d_in[12];
  const float* bhh2b = (const float*)d_in[13];
  const float* W1 = (const float*)d_in[14];
  const float* b1 = (const float*)d_in[15];
  const float* W2 = (const float*)d_in[16];
  const float* b2 = (const float*)d_in[17];
  const float* W3 = (const float*)d_in[18];
  const float* b3 = (const float*)d_in[19];
  const float* W4 = (const float*)d_in[20];
  const float* b4 = (const float*)d_in[21];
  const float* W5 = (const float*)d_in[22];
  const float* b5 = (const float*)d_in[23];

  int B = in_sizes[0] / 640;  // [B,128,5]
  size_t req = ((size_t)B * 640 + (size_t)B * 5) * sizeof(float);

  if (d_ws && ws_size >= req) {
    float* h2a = (float*)d_ws;                  // [B][128][5]
    float* h1l = h2a + (size_t)B * 640;         // [B][5]
    int N1 = (B + 11) / 12;                     // waves per cell
    int nA = (2 * N1 + 2) / 3;                  // 3 waves/block
    int nB = (B + 35) / 36;                     // 36 elements/block
    rnn_a_kernel<<<nA, 192, 0, stream>>>(x1, x2, Wih1, Whh1, bih1, bhh1, Wih2a,
                                         Whh2a, bih2a, bhh2a, h2a, h1l, B, N1);
    rnn_b_kernel<<<nB, 192, 0, stream>>>(x1, x2, Wih2b, Whh2b, bih2b, bhh2b,
                                         W1, b1, W2, b2, W3, b3, W4, b4, W5,
                                         b5, h2a, h1l, (float*)d_out, B);
  } else {
    int nB = (B + 23) / 24;
    rnn_stag_kernel<<<nB, 192, 0, stream>>>(
        x1, x2, Wih1, Whh1, bih1, bhh1, Wih2a, Whh2a, bih2a, bhh2a, Wih2b,
        Whh2b, bih2b, bhh2b, W1, b1, W2, b2, W3, b3, W4, b4, W5, b5,
        (float*)d_out, B);
  }
}